// Round 7
// baseline (306.025 us; speedup 1.0000x reference)
//
#include <hip/hip_runtime.h>

// TensorConvolutionTrainLayer: S=512,P=196,Q=48,CB=8,R=32,C=10,N=8
// R10b: intra-wave software pipeline on R9's barrier-free structure (R10 with
// the cvt_pkrtz type fix: the builtin returns __fp16x2, union member adjusted).
// Per iteration cc: (1) issue 5 ds_reads for chunk cc-1 (old data; reads
// precede this iter's writes in program order -> single buffer safe),
// (2) G train for cc covers the read latency, (3) NS(cc-1) from ready regs,
// (4) pack+write(cc) with cvt_pkrtz. Iteration 8 = NS tail only.
//   a=mi*2+fqh, b=fql*4+rg, l=ni*2+(fr>>3), rr=fr&7
//   Gsh[m=b*8+rr][k'=l*8+sigma(a)], sigma(a)=fqh*4+mi -> mi contiguous
//   epilogue: St3[c][(wave*8+rr)*8+sigma(b)] <- ns (wave-disjoint columns)

typedef _Float16 half8 __attribute__((ext_vector_type(8)));
typedef _Float16 half4 __attribute__((ext_vector_type(4)));
typedef __fp16   fp16x2 __attribute__((ext_vector_type(2)));
typedef float floatx4 __attribute__((ext_vector_type(4)));

#define KP 224    // P padded to 7*32
#define QP 64     // Q padded to 2*32
#define LDA2 232  // Mt2/Ash row stride (halfs) = 29 x 16B chunks
#define GSTR 40   // Gsh row stride (halfs): 80B rows -> b128-aligned
#define SSTR 264  // St3 row stride (halfs): 528B, 16B-aligned

__device__ __forceinline__ void gld_lds16(const void* g, void* l) {
  __builtin_amdgcn_global_load_lds((const __attribute__((address_space(1))) void*)g,
                                   (__attribute__((address_space(3))) void*)l, 16, 0, 0);
}

// ---------------- generic MFMA GEMM (unchanged) ----------------
template<int K, int MODE>
__global__ __launch_bounds__(256)
void gemm_mfma(const _Float16* __restrict__ A, const _Float16* __restrict__ Bt,
               void* __restrict__ out0, void* __restrict__ out1, void* __restrict__ out2)
{
  __shared__ __align__(16) _Float16 Ash[128 * 32];
  __shared__ __align__(16) _Float16 Bsh[128 * 32];
  const int tid  = threadIdx.x;
  const int wave = tid >> 6;
  const int lane = tid & 63;
  const int m0 = blockIdx.y * 128;
  const int n0 = blockIdx.x * 128;
  const int wm = (wave >> 1) * 64;
  const int wn = (wave & 1) * 64;
  const int fr = lane & 15;
  const int fq = lane >> 4;

  floatx4 acc[4][4] = {};

  for (int kt = 0; kt < K; kt += 32) {
    __syncthreads();
#pragma unroll
    for (int j = 0; j < 2; j++) {
      const int c   = j * 256 + tid;
      const int row = c >> 2;
      const int ko  = (c & 3) * 8;
      gld_lds16(A  + (size_t)(m0 + row) * K + kt + ko,
                (char*)Ash + (size_t)(j * 256 + wave * 64) * 16);
      gld_lds16(Bt + (size_t)(n0 + row) * K + kt + ko,
                (char*)Bsh + (size_t)(j * 256 + wave * 64) * 16);
    }
    __syncthreads();
    half8 af[4], bf[4];
#pragma unroll
    for (int i = 0; i < 4; i++)
      af[i] = *(const half8*)&Ash[(wm + i * 16 + fr) * 32 + fq * 8];
#pragma unroll
    for (int i = 0; i < 4; i++)
      bf[i] = *(const half8*)&Bsh[(wn + i * 16 + fr) * 32 + fq * 8];
#pragma unroll
    for (int i = 0; i < 4; i++)
#pragma unroll
      for (int j = 0; j < 4; j++)
        acc[i][j] = __builtin_amdgcn_mfma_f32_16x16x32_f16(af[i], bf[j], acc[i][j], 0, 0, 0);
  }

#pragma unroll
  for (int i = 0; i < 4; i++) {
#pragma unroll
    for (int j = 0; j < 4; j++) {
#pragma unroll
      for (int r = 0; r < 4; r++) {
        const int m = m0 + wm + i * 16 + fq * 4 + r;
        const int n = n0 + wn + j * 16 + fr;
        const float v = acc[i][j][r];
        if constexpr (MODE == 0) {
          const unsigned s = (unsigned)n / 196u;
          const unsigned p = (unsigned)n - s * 196u;
          if (m < 8)
            ((_Float16*)out1)[((size_t)m * 512 + s) * KP + p] = (_Float16)v;
          else if (m < 392)
            ((_Float16*)out0)[((size_t)s * 384 + (m - 8)) * LDA2 + p] = (_Float16)v;
          else if (m < 400)
            ((_Float16*)out2)[((size_t)(m - 392) * 512 + s) * KP + p] = (_Float16)v;
        } else if constexpr (MODE == 2) {
          if (n < 320)
            ((float*)out0)[(size_t)(m & 511) * 2560 + (m >> 9) * 320 + n] = v;
        } else {
          if (n < 32)
            ((float*)out0)[(size_t)m * 32 + n] = v;
        }
      }
    }
  }
}

// ---------------- fused chain kernel (4 waves, pipelined barrier-free chunks) ----------------
__device__ __forceinline__ void stageA(const _Float16* __restrict__ base,
                                       _Float16* __restrict__ ash, int tid) {
  const int wave = tid >> 6;
#pragma unroll
  for (int it = 0; it < 7; it++) {
    const int c = it * 256 + tid;
    gld_lds16(base + (size_t)c * 8, (char*)ash + (size_t)(it * 256 + wave * 64) * 16);
  }
  if (tid < 64)
    gld_lds16(base + (size_t)(1792 + tid) * 8, (char*)ash + (size_t)1792 * 16);
}

__global__ __launch_bounds__(256, 2)
void chain_kernel(const _Float16* __restrict__ Mt2, const _Float16* __restrict__ Akr,
                  const float* __restrict__ St0, const float* __restrict__ GN,
                  float* __restrict__ out)
{
  __shared__ __align__(16) _Float16 Ash[64 * LDA2];        // 29696 B
  __shared__ __align__(16) _Float16 Gsh[4][64 * GSTR];     // 20480 B (per-wave private)
  __shared__ __align__(16) _Float16 St3[16 * SSTR];        // 8448 B
  __shared__ float oc[10];

  const int tid  = threadIdx.x;
  const int wave = tid >> 6;
  const int lane = tid & 63;
  const int s    = blockIdx.x;
  const int fr   = lane & 15;
  const int fq   = lane >> 4;
  const int fre  = fr & 7;
  const int frh  = fr >> 3;
  const int fqh  = fq >> 1;
  const int fql  = fq & 1;

  // init: St3[c][r*8+sigma(b)] from St0[s][b*320+r*10+c]; tid=(b,r)
  {
    const int b = tid >> 5, r = tid & 31;
    const int kcol = r * 8 + ((b & 1) * 4 + (b >> 1));
    const float* src = St0 + (size_t)s * 2560 + (size_t)tid * 10;
#pragma unroll
    for (int c = 0; c < 10; c++) St3[c * SSTR + kcol] = (_Float16)src[c];
    if (tid < 10) oc[tid] = 0.f;
  }
  stageA(Mt2 + (size_t)s * 384 * LDA2, Ash, tid);

  // B lane offsets: G B-cols n = ni*16+fr -> l = ni*2+frh, rr = fre (wave's r-slice)
  const size_t lb0 = (size_t)((0 * 2 + frh) * 32 + wave * 8 + fre) * KP + fq * 8;
  const size_t lb1 = (size_t)((1 * 2 + frh) * 32 + wave * 8 + fre) * KP + fq * 8;

  // full-chunk-distance B prefetch: bf[kt][ni] for (k=0, cc=0)
  half8 bf[7][2];
#pragma unroll
  for (int kt = 0; kt < 7; kt++) {
    bf[kt][0] = *(const half8*)(Akr + lb0 + kt * 32);
    bf[kt][1] = *(const half8*)(Akr + lb1 + kt * 32);
  }
  __syncthreads();   // Ash + St3 ready (compiler drains vmcnt before barrier)

  _Float16* gw = &Gsh[wave][0];

  for (int k = 0; k < 6; k++) {
    // af hoist: whole 64x224 A-tile -> regs/AGPRs once per k (R5/R9-proven)
    half8 af[7][4];
#pragma unroll
    for (int kt = 0; kt < 7; kt++)
#pragma unroll
      for (int mi = 0; mi < 4; mi++)
        af[kt][mi] = *(const half8*)&Ash[(mi * 16 + fr) * LDA2 + kt * 32 + fq * 8];
    __syncthreads();   // bar1: af reads done -> Ash free; St3(k) visible
    if (k < 5) stageA(Mt2 + ((size_t)s * 384 + 64 * (k + 1)) * LDA2, Ash, tid);

    floatx4 ns[4] = {};

#pragma unroll 1
    for (int cc = 0; cc <= 8; cc++) {
      // ---- early reads for NS(cc-1): old Gsh data; program order places them
      // before this iteration's pack-writes, so a single buffer is safe ----
      half8 aaP[4], bsP;
      if (cc > 0) {
        bsP = *(const half8*)&St3[fr * SSTR + (cc - 1) * 32 + fq * 8];
#pragma unroll
        for (int t = 0; t < 4; t++)
          aaP[t] = *(const half8*)&gw[(t * 16 + fr) * GSTR + fq * 8];
        __builtin_amdgcn_sched_barrier(0);   // pin reads above the G train
      }

      floatx4 acc[4][2] = {};
      if (cc < 8) {
        int ncc = cc + 1, nk = k;
        if (ncc == 8) { ncc = 0; nk = k + 1; }
        const _Float16* Bn = Akr + ((size_t)nk * 1024 + ncc * 128) * KP;
        const bool pf = (nk < 6);
        // ---- G-phase: wave's 64 ab x 32 (4l x own 8r) slice, K=224 ----
#pragma unroll
        for (int kt = 0; kt < 7; kt++) {
#pragma unroll
          for (int mi = 0; mi < 4; mi++) {
            acc[mi][0] = __builtin_amdgcn_mfma_f32_16x16x32_f16(af[kt][mi], bf[kt][0], acc[mi][0], 0, 0, 0);
            acc[mi][1] = __builtin_amdgcn_mfma_f32_16x16x32_f16(af[kt][mi], bf[kt][1], acc[mi][1], 0, 0, 0);
          }
          if (pf) {   // roll bf[kt] to next chunk right after last use
            bf[kt][0] = *(const half8*)(Bn + lb0 + kt * 32);
            bf[kt][1] = *(const half8*)(Bn + lb1 + kt * 32);
          }
        }
      }

      // ---- NS(cc-1): registers ready (read latency covered by G train) ----
      if (cc > 0) {
#pragma unroll
        for (int t = 0; t < 4; t++)
          ns[t] = __builtin_amdgcn_mfma_f32_16x16x32_f16(aaP[t], bsP, ns[t], 0, 0, 0);
      }

      // ---- pack + write cc to PRIVATE Gsh (cvt_pkrtz: 2 f32 -> f16x2) ----
      if (cc < 8) {
#pragma unroll
        for (int ni = 0; ni < 2; ni++)
#pragma unroll
          for (int rg = 0; rg < 4; rg++) {
            union { half4 h4; fp16x2 p[2]; } u;
            u.p[0] = __builtin_amdgcn_cvt_pkrtz(acc[0][ni][rg], acc[1][ni][rg]);
            u.p[1] = __builtin_amdgcn_cvt_pkrtz(acc[2][ni][rg], acc[3][ni][rg]);
            *(half4*)&gw[((fql * 4 + rg) * 8 + fre) * GSTR + (ni * 2 + frh) * 8 + fqh * 4] = u.h4;
          }
      }
    }

    __syncthreads();   // bar2: all NS reads of St3 done; stage(k+1) drained
    // epilogue: ns -> St3 (wave-disjoint columns). m=t*16+fq*4+rg -> b=m>>3, rr=m&7
    if (fr < 10) {
#pragma unroll
      for (int t = 0; t < 4; t++) {
#pragma unroll
        for (int rg = 0; rg < 4; rg++) {
          const int m = t * 16 + fq * 4 + rg;
          const int b = m >> 3, rr = m & 7;
          St3[fr * SSTR + (wave * 8 + rr) * 8 + (b & 1) * 4 + (b >> 1)] = (_Float16)ns[t][rg];
        }
      }
    }
    // next k's bar1 orders these writes before any NS read of k+1
  }
  __syncthreads();

  // final: out[s,c] = sum_{a,l} St3[c][l*8+sigma(a)] * GN[a][s][l]
  {
    const int a = tid >> 5, l = tid & 31;
    const float gn = GN[((size_t)a * 512 + s) * 32 + l];
    const int kcol = l * 8 + ((a & 1) * 4 + (a >> 1));
#pragma unroll
    for (int c = 0; c < 10; c++) {
      float v = gn * (float)St3[c * SSTR + kcol];
#pragma unroll
      for (int o2 = 1; o2 < 64; o2 <<= 1) v += __shfl_xor(v, o2, 64);
      if (lane == 0) atomicAdd(&oc[c], v);
    }
    __syncthreads();
    if (tid < 10) out[(size_t)s * 10 + tid] = oc[tid];
  }
}

// ---------------- prep kernels (unchanged) ----------------
__global__ void prep_xh(const float* __restrict__ x, _Float16* __restrict__ xh) {
  const int idx = blockIdx.x * 256 + threadIdx.x;
  const int q = idx & 63, sp = idx >> 6;
  xh[idx] = (q < 48) ? (_Float16)x[sp * 48 + q] : (_Float16)0.f;
}

__global__ void prep_ckt(const float* __restrict__ cf, const float* __restrict__ cm,
                         const float* __restrict__ cl, _Float16* __restrict__ Ckt) {
  const int idx = blockIdx.x * 256 + threadIdx.x;
  const int q = idx & 63;
  const int row = idx >> 6;
  float v = 0.f;
  if (q < 48) {
    if (row < 8) v = cf[q * 8 + row];
    else if (row < 392) {
      const int rr = row - 8;
      const int k = rr >> 6, ab = rr & 63, a = ab >> 3, b = ab & 7;
      v = cm[((k * 8 + a) * 48 + q) * 8 + b];
    } else if (row < 400) v = cl[(row - 392) * 48 + q];
  }
  Ckt[idx] = (_Float16)v;
}

__global__ void prep_akr(const float* __restrict__ tm, _Float16* __restrict__ Akr) {
  const int idx = blockIdx.x * 256 + threadIdx.x;
  const int p = idx % 224;
  const int lr = (idx / 224) & 1023;
  const int k = idx / (224 * 1024);
  const int l = lr >> 5, r = lr & 31;
  float v = 0.f;
  if (p < 196) v = tm[(((k * 32 + l) * 196) + p) * 32 + r];
  Akr[idx] = (_Float16)v;
}

__global__ void prep_bt0(const float* __restrict__ tf, _Float16* __restrict__ Bt0) {
  const int idx = blockIdx.x * 256 + threadIdx.x;
  const int p = idx % 224;
  const int n = idx / 224;
  float v = 0.f;
  if (n < 320 && p < 196) {
    const int r = n / 10, c = n % 10;
    v = tf[(c * 196 + p) * 32 + r];
  }
  Bt0[idx] = (_Float16)v;
}

__global__ void prep_btl(const float* __restrict__ tl, _Float16* __restrict__ Btl) {
  const int idx = blockIdx.x * 256 + threadIdx.x;
  const int p = idx % 224;
  const int n = idx / 224;
  float v = 0.f;
  if (n < 32 && p < 196) v = tl[n * 196 + p];
  Btl[idx] = (_Float16)v;
}

__global__ void zero_pads(_Float16* __restrict__ Mt2, _Float16* __restrict__ MtF,
                          _Float16* __restrict__ MtL) {
  const int idx = blockIdx.x * 256 + threadIdx.x;
  if (idx < 196608) {
    _Float16* p = Mt2 + (size_t)idx * LDA2 + 196;
#pragma unroll
    for (int j = 0; j < 36; j++) p[j] = (_Float16)0.f;
  }
  if (idx < 4096) {
    _Float16* p = MtF + (size_t)idx * KP + 196;
    _Float16* q = MtL + (size_t)idx * KP + 196;
#pragma unroll
    for (int j = 0; j < 28; j++) { p[j] = (_Float16)0.f; q[j] = (_Float16)0.f; }
  }
}

extern "C" void kernel_launch(void* const* d_in, const int* in_sizes, int n_in,
                              void* d_out, int out_size, void* d_ws, size_t ws_size,
                              hipStream_t stream)
{
  const float* x  = (const float*)d_in[0];
  const float* cf = (const float*)d_in[1];
  const float* cm = (const float*)d_in[2];
  const float* cl = (const float*)d_in[3];
  const float* tf = (const float*)d_in[4];
  const float* tm = (const float*)d_in[5];
  const float* tl = (const float*)d_in[6];
  float* out = (float*)d_out;

  char* w = (char*)d_ws;
  auto alloc = [&](size_t bytes) { char* p = w; w += (bytes + 255) & ~(size_t)255; return p; };
  _Float16* xh  = (_Float16*)alloc(100352ull * 64 * 2);
  _Float16* Ckt = (_Float16*)alloc(512ull * 64 * 2);
  _Float16* Mt2 = (_Float16*)alloc(512ull * 384 * LDA2 * 2);
  _Float16* MtF = (_Float16*)alloc(8ull * 512 * KP * 2);
  _Float16* MtL = (_Float16*)alloc(8ull * 512 * KP * 2);
  _Float16* Akr = (_Float16*)alloc(6ull * 1024 * KP * 2);
  _Float16* Bt0 = (_Float16*)alloc(384ull * KP * 2);
  _Float16* Btl = (_Float16*)alloc(128ull * KP * 2);
  float* stA    = (float*)alloc(512ull * 2560 * 4);
  float* GN     = (float*)alloc(4096ull * 32 * 4);
  (void)ws_size; (void)in_sizes; (void)n_in; (void)out_size;

  prep_xh <<<25088, 256, 0, stream>>>(x, xh);
  prep_ckt<<<  128, 256, 0, stream>>>(cf, cm, cl, Ckt);
  prep_akr<<< 5376, 256, 0, stream>>>(tm, Akr);
  prep_bt0<<<  336, 256, 0, stream>>>(tf, Bt0);
  prep_btl<<<  112, 256, 0, stream>>>(tl, Btl);
  zero_pads<<<  768, 256, 0, stream>>>(Mt2, MtF, MtL);

  gemm_mfma<QP, 0><<<dim3(784, 4), 256, 0, stream>>>(Ckt, xh, Mt2, MtF, MtL);
  gemm_mfma<KP, 2><<<dim3(3, 32), 256, 0, stream>>>(MtF, Bt0, stA, nullptr, nullptr);
  gemm_mfma<KP, 3><<<dim3(1, 32), 256, 0, stream>>>(MtL, Btl, GN, nullptr, nullptr);

  chain_kernel<<<512, 256, 0, stream>>>(Mt2, Akr, stA, GN, out);
}

// Round 8
// 271.106 us; speedup vs baseline: 1.1288x; 1.1288x over previous
//
#include <hip/hip_runtime.h>

// TensorConvolutionTrainLayer: S=512,P=196,Q=48,CB=8,R=32,C=10,N=8
// R11: R10b's pipeline caused scratch spill (WRITE_SIZE 0.5->30.7 MB): aaP/bsP
// live across the G train on top of af(112)+bf(56)+acc(32)+ns(16) blew the
// unified register file. Keep the pipeline, cut bf[7][2] (56 reg) to rolling
// bq[2][2] (16 reg, R5-proven distance-2): peak live ~221 < 256, no spill.
// Barrier-free cc loop means no vmcnt(0) drain to defeat the rolling prefetch;
// next-chunk refill issues right after the G train, covered by NS+pack.
// Per iteration cc: (1) ds_reads for NS(cc-1) (old Gsh data, single buffer
// safe by program order), (2) G train covers read latency, (3) NS(cc-1) from
// ready regs, (4) pack+write(cc) via cvt_pkrtz. Iteration 8 = NS tail.
//   a=mi*2+fqh, b=fql*4+rg, l=ni*2+(fr>>3), rr=fr&7
//   Gsh[m=b*8+rr][k'=l*8+sigma(a)], sigma(a)=fqh*4+mi -> mi contiguous
//   epilogue: St3[c][(wave*8+rr)*8+sigma(b)] <- ns (wave-disjoint columns)

typedef _Float16 half8 __attribute__((ext_vector_type(8)));
typedef _Float16 half4 __attribute__((ext_vector_type(4)));
typedef __fp16   fp16x2 __attribute__((ext_vector_type(2)));
typedef float floatx4 __attribute__((ext_vector_type(4)));

#define KP 224    // P padded to 7*32
#define QP 64     // Q padded to 2*32
#define LDA2 232  // Mt2/Ash row stride (halfs) = 29 x 16B chunks
#define GSTR 40   // Gsh row stride (halfs): 80B rows -> b128-aligned
#define SSTR 264  // St3 row stride (halfs): 528B, 16B-aligned

__device__ __forceinline__ void gld_lds16(const void* g, void* l) {
  __builtin_amdgcn_global_load_lds((const __attribute__((address_space(1))) void*)g,
                                   (__attribute__((address_space(3))) void*)l, 16, 0, 0);
}

// ---------------- generic MFMA GEMM (unchanged) ----------------
template<int K, int MODE>
__global__ __launch_bounds__(256)
void gemm_mfma(const _Float16* __restrict__ A, const _Float16* __restrict__ Bt,
               void* __restrict__ out0, void* __restrict__ out1, void* __restrict__ out2)
{
  __shared__ __align__(16) _Float16 Ash[128 * 32];
  __shared__ __align__(16) _Float16 Bsh[128 * 32];
  const int tid  = threadIdx.x;
  const int wave = tid >> 6;
  const int lane = tid & 63;
  const int m0 = blockIdx.y * 128;
  const int n0 = blockIdx.x * 128;
  const int wm = (wave >> 1) * 64;
  const int wn = (wave & 1) * 64;
  const int fr = lane & 15;
  const int fq = lane >> 4;

  floatx4 acc[4][4] = {};

  for (int kt = 0; kt < K; kt += 32) {
    __syncthreads();
#pragma unroll
    for (int j = 0; j < 2; j++) {
      const int c   = j * 256 + tid;
      const int row = c >> 2;
      const int ko  = (c & 3) * 8;
      gld_lds16(A  + (size_t)(m0 + row) * K + kt + ko,
                (char*)Ash + (size_t)(j * 256 + wave * 64) * 16);
      gld_lds16(Bt + (size_t)(n0 + row) * K + kt + ko,
                (char*)Bsh + (size_t)(j * 256 + wave * 64) * 16);
    }
    __syncthreads();
    half8 af[4], bf[4];
#pragma unroll
    for (int i = 0; i < 4; i++)
      af[i] = *(const half8*)&Ash[(wm + i * 16 + fr) * 32 + fq * 8];
#pragma unroll
    for (int i = 0; i < 4; i++)
      bf[i] = *(const half8*)&Bsh[(wn + i * 16 + fr) * 32 + fq * 8];
#pragma unroll
    for (int i = 0; i < 4; i++)
#pragma unroll
      for (int j = 0; j < 4; j++)
        acc[i][j] = __builtin_amdgcn_mfma_f32_16x16x32_f16(af[i], bf[j], acc[i][j], 0, 0, 0);
  }

#pragma unroll
  for (int i = 0; i < 4; i++) {
#pragma unroll
    for (int j = 0; j < 4; j++) {
#pragma unroll
      for (int r = 0; r < 4; r++) {
        const int m = m0 + wm + i * 16 + fq * 4 + r;
        const int n = n0 + wn + j * 16 + fr;
        const float v = acc[i][j][r];
        if constexpr (MODE == 0) {
          const unsigned s = (unsigned)n / 196u;
          const unsigned p = (unsigned)n - s * 196u;
          if (m < 8)
            ((_Float16*)out1)[((size_t)m * 512 + s) * KP + p] = (_Float16)v;
          else if (m < 392)
            ((_Float16*)out0)[((size_t)s * 384 + (m - 8)) * LDA2 + p] = (_Float16)v;
          else if (m < 400)
            ((_Float16*)out2)[((size_t)(m - 392) * 512 + s) * KP + p] = (_Float16)v;
        } else if constexpr (MODE == 2) {
          if (n < 320)
            ((float*)out0)[(size_t)(m & 511) * 2560 + (m >> 9) * 320 + n] = v;
        } else {
          if (n < 32)
            ((float*)out0)[(size_t)m * 32 + n] = v;
        }
      }
    }
  }
}

// ---------------- fused chain kernel (4 waves, pipelined barrier-free chunks) ----------------
__device__ __forceinline__ void stageA(const _Float16* __restrict__ base,
                                       _Float16* __restrict__ ash, int tid) {
  const int wave = tid >> 6;
#pragma unroll
  for (int it = 0; it < 7; it++) {
    const int c = it * 256 + tid;
    gld_lds16(base + (size_t)c * 8, (char*)ash + (size_t)(it * 256 + wave * 64) * 16);
  }
  if (tid < 64)
    gld_lds16(base + (size_t)(1792 + tid) * 8, (char*)ash + (size_t)1792 * 16);
}

__global__ __launch_bounds__(256, 2)
void chain_kernel(const _Float16* __restrict__ Mt2, const _Float16* __restrict__ Akr,
                  const float* __restrict__ St0, const float* __restrict__ GN,
                  float* __restrict__ out)
{
  __shared__ __align__(16) _Float16 Ash[64 * LDA2];        // 29696 B
  __shared__ __align__(16) _Float16 Gsh[4][64 * GSTR];     // 20480 B (per-wave private)
  __shared__ __align__(16) _Float16 St3[16 * SSTR];        // 8448 B
  __shared__ float oc[10];

  const int tid  = threadIdx.x;
  const int wave = tid >> 6;
  const int lane = tid & 63;
  const int s    = blockIdx.x;
  const int fr   = lane & 15;
  const int fq   = lane >> 4;
  const int fre  = fr & 7;
  const int frh  = fr >> 3;
  const int fqh  = fq >> 1;
  const int fql  = fq & 1;

  // init: St3[c][r*8+sigma(b)] from St0[s][b*320+r*10+c]; tid=(b,r)
  {
    const int b = tid >> 5, r = tid & 31;
    const int kcol = r * 8 + ((b & 1) * 4 + (b >> 1));
    const float* src = St0 + (size_t)s * 2560 + (size_t)tid * 10;
#pragma unroll
    for (int c = 0; c < 10; c++) St3[c * SSTR + kcol] = (_Float16)src[c];
    if (tid < 10) oc[tid] = 0.f;
  }
  stageA(Mt2 + (size_t)s * 384 * LDA2, Ash, tid);

  // B lane offsets: G B-cols n = ni*16+fr -> l = ni*2+frh, rr = fre (wave's r-slice)
  const size_t lb0 = (size_t)((0 * 2 + frh) * 32 + wave * 8 + fre) * KP + fq * 8;
  const size_t lb1 = (size_t)((1 * 2 + frh) * 32 + wave * 8 + fre) * KP + fq * 8;

  // rolling B prefetch (2-deep): bq[kt&1][ni], preload (k=0, cc=0, kt=0,1)
  half8 bq[2][2];
#pragma unroll
  for (int t2 = 0; t2 < 2; t2++) {
    bq[t2][0] = *(const half8*)(Akr + lb0 + t2 * 32);
    bq[t2][1] = *(const half8*)(Akr + lb1 + t2 * 32);
  }
  __syncthreads();   // Ash + St3 ready (compiler drains vmcnt before barrier)

  _Float16* gw = &Gsh[wave][0];

  for (int k = 0; k < 6; k++) {
    // af hoist: whole 64x224 A-tile -> regs/AGPRs once per k (R5/R9-proven)
    half8 af[7][4];
#pragma unroll
    for (int kt = 0; kt < 7; kt++)
#pragma unroll
      for (int mi = 0; mi < 4; mi++)
        af[kt][mi] = *(const half8*)&Ash[(mi * 16 + fr) * LDA2 + kt * 32 + fq * 8];
    __syncthreads();   // bar1: af reads done -> Ash free; St3(k) visible
    if (k < 5) stageA(Mt2 + ((size_t)s * 384 + 64 * (k + 1)) * LDA2, Ash, tid);

    floatx4 ns[4] = {};

#pragma unroll 1
    for (int cc = 0; cc <= 8; cc++) {
      // ---- early reads for NS(cc-1): old Gsh data; program order places them
      // before this iteration's pack-writes, so a single buffer is safe ----
      half8 aaP[4], bsP;
      if (cc > 0) {
        bsP = *(const half8*)&St3[fr * SSTR + (cc - 1) * 32 + fq * 8];
#pragma unroll
        for (int t = 0; t < 4; t++)
          aaP[t] = *(const half8*)&gw[(t * 16 + fr) * GSTR + fq * 8];
        __builtin_amdgcn_sched_barrier(0);   // pin reads above the G train
      }

      floatx4 acc[4][2] = {};
      if (cc < 8) {
        const _Float16* Bc = Akr + ((size_t)k * 1024 + cc * 128) * KP;
        // ---- G-phase: wave's 64 ab x 32 (4l x own 8r) slice, K=224 ----
#pragma unroll
        for (int kt = 0; kt < 7; kt++) {
#pragma unroll
          for (int mi = 0; mi < 4; mi++) {
            acc[mi][0] = __builtin_amdgcn_mfma_f32_16x16x32_f16(af[kt][mi], bq[kt & 1][0], acc[mi][0], 0, 0, 0);
            acc[mi][1] = __builtin_amdgcn_mfma_f32_16x16x32_f16(af[kt][mi], bq[kt & 1][1], acc[mi][1], 0, 0, 0);
          }
          if (kt < 5) {   // rolling prefetch, distance 2 kt within the chunk
            bq[kt & 1][0] = *(const half8*)(Bc + lb0 + (kt + 2) * 32);
            bq[kt & 1][1] = *(const half8*)(Bc + lb1 + (kt + 2) * 32);
          }
        }
        // refill kt=0,1 of the NEXT chunk; NS+pack below cover the latency
        {
          int ncc = cc + 1, nk = k;
          if (ncc == 8) { ncc = 0; nk = k + 1; }
          if (nk < 6) {
            const _Float16* Bn = Akr + ((size_t)nk * 1024 + ncc * 128) * KP;
#pragma unroll
            for (int t2 = 0; t2 < 2; t2++) {
              bq[t2][0] = *(const half8*)(Bn + lb0 + t2 * 32);
              bq[t2][1] = *(const half8*)(Bn + lb1 + t2 * 32);
            }
          }
        }
      }

      // ---- NS(cc-1): registers ready (read latency covered by G train) ----
      if (cc > 0) {
#pragma unroll
        for (int t = 0; t < 4; t++)
          ns[t] = __builtin_amdgcn_mfma_f32_16x16x32_f16(aaP[t], bsP, ns[t], 0, 0, 0);
      }

      // ---- pack + write cc to PRIVATE Gsh (cvt_pkrtz: 2 f32 -> f16x2) ----
      if (cc < 8) {
#pragma unroll
        for (int ni = 0; ni < 2; ni++)
#pragma unroll
          for (int rg = 0; rg < 4; rg++) {
            union { half4 h4; fp16x2 p[2]; } u;
            u.p[0] = __builtin_amdgcn_cvt_pkrtz(acc[0][ni][rg], acc[1][ni][rg]);
            u.p[1] = __builtin_amdgcn_cvt_pkrtz(acc[2][ni][rg], acc[3][ni][rg]);
            *(half4*)&gw[((fql * 4 + rg) * 8 + fre) * GSTR + (ni * 2 + frh) * 8 + fqh * 4] = u.h4;
          }
      }
    }

    __syncthreads();   // bar2: all NS reads of St3 done; stage(k+1) drained
    // epilogue: ns -> St3 (wave-disjoint columns). m=t*16+fq*4+rg -> b=m>>3, rr=m&7
    if (fr < 10) {
#pragma unroll
      for (int t = 0; t < 4; t++) {
#pragma unroll
        for (int rg = 0; rg < 4; rg++) {
          const int m = t * 16 + fq * 4 + rg;
          const int b = m >> 3, rr = m & 7;
          St3[fr * SSTR + (wave * 8 + rr) * 8 + (b & 1) * 4 + (b >> 1)] = (_Float16)ns[t][rg];
        }
      }
    }
    // next k's bar1 orders these writes before any NS read of k+1
  }
  __syncthreads();

  // final: out[s,c] = sum_{a,l} St3[c][l*8+sigma(a)] * GN[a][s][l]
  {
    const int a = tid >> 5, l = tid & 31;
    const float gn = GN[((size_t)a * 512 + s) * 32 + l];
    const int kcol = l * 8 + ((a & 1) * 4 + (a >> 1));
#pragma unroll
    for (int c = 0; c < 10; c++) {
      float v = gn * (float)St3[c * SSTR + kcol];
#pragma unroll
      for (int o2 = 1; o2 < 64; o2 <<= 1) v += __shfl_xor(v, o2, 64);
      if (lane == 0) atomicAdd(&oc[c], v);
    }
    __syncthreads();
    if (tid < 10) out[(size_t)s * 10 + tid] = oc[tid];
  }
}

// ---------------- prep kernels (unchanged) ----------------
__global__ void prep_xh(const float* __restrict__ x, _Float16* __restrict__ xh) {
  const int idx = blockIdx.x * 256 + threadIdx.x;
  const int q = idx & 63, sp = idx >> 6;
  xh[idx] = (q < 48) ? (_Float16)x[sp * 48 + q] : (_Float16)0.f;
}

__global__ void prep_ckt(const float* __restrict__ cf, const float* __restrict__ cm,
                         const float* __restrict__ cl, _Float16* __restrict__ Ckt) {
  const int idx = blockIdx.x * 256 + threadIdx.x;
  const int q = idx & 63;
  const int row = idx >> 6;
  float v = 0.f;
  if (q < 48) {
    if (row < 8) v = cf[q * 8 + row];
    else if (row < 392) {
      const int rr = row - 8;
      const int k = rr >> 6, ab = rr & 63, a = ab >> 3, b = ab & 7;
      v = cm[((k * 8 + a) * 48 + q) * 8 + b];
    } else if (row < 400) v = cl[(row - 392) * 48 + q];
  }
  Ckt[idx] = (_Float16)v;
}

__global__ void prep_akr(const float* __restrict__ tm, _Float16* __restrict__ Akr) {
  const int idx = blockIdx.x * 256 + threadIdx.x;
  const int p = idx % 224;
  const int lr = (idx / 224) & 1023;
  const int k = idx / (224 * 1024);
  const int l = lr >> 5, r = lr & 31;
  float v = 0.f;
  if (p < 196) v = tm[(((k * 32 + l) * 196) + p) * 32 + r];
  Akr[idx] = (_Float16)v;
}

__global__ void prep_bt0(const float* __restrict__ tf, _Float16* __restrict__ Bt0) {
  const int idx = blockIdx.x * 256 + threadIdx.x;
  const int p = idx % 224;
  const int n = idx / 224;
  float v = 0.f;
  if (n < 320 && p < 196) {
    const int r = n / 10, c = n % 10;
    v = tf[(c * 196 + p) * 32 + r];
  }
  Bt0[idx] = (_Float16)v;
}

__global__ void prep_btl(const float* __restrict__ tl, _Float16* __restrict__ Btl) {
  const int idx = blockIdx.x * 256 + threadIdx.x;
  const int p = idx % 224;
  const int n = idx / 224;
  float v = 0.f;
  if (n < 32 && p < 196) v = tl[n * 196 + p];
  Btl[idx] = (_Float16)v;
}

__global__ void zero_pads(_Float16* __restrict__ Mt2, _Float16* __restrict__ MtF,
                          _Float16* __restrict__ MtL) {
  const int idx = blockIdx.x * 256 + threadIdx.x;
  if (idx < 196608) {
    _Float16* p = Mt2 + (size_t)idx * LDA2 + 196;
#pragma unroll
    for (int j = 0; j < 36; j++) p[j] = (_Float16)0.f;
  }
  if (idx < 4096) {
    _Float16* p = MtF + (size_t)idx * KP + 196;
    _Float16* q = MtL + (size_t)idx * KP + 196;
#pragma unroll
    for (int j = 0; j < 28; j++) { p[j] = (_Float16)0.f; q[j] = (_Float16)0.f; }
  }
}

extern "C" void kernel_launch(void* const* d_in, const int* in_sizes, int n_in,
                              void* d_out, int out_size, void* d_ws, size_t ws_size,
                              hipStream_t stream)
{
  const float* x  = (const float*)d_in[0];
  const float* cf = (const float*)d_in[1];
  const float* cm = (const float*)d_in[2];
  const float* cl = (const float*)d_in[3];
  const float* tf = (const float*)d_in[4];
  const float* tm = (const float*)d_in[5];
  const float* tl = (const float*)d_in[6];
  float* out = (float*)d_out;

  char* w = (char*)d_ws;
  auto alloc = [&](size_t bytes) { char* p = w; w += (bytes + 255) & ~(size_t)255; return p; };
  _Float16* xh  = (_Float16*)alloc(100352ull * 64 * 2);
  _Float16* Ckt = (_Float16*)alloc(512ull * 64 * 2);
  _Float16* Mt2 = (_Float16*)alloc(512ull * 384 * LDA2 * 2);
  _Float16* MtF = (_Float16*)alloc(8ull * 512 * KP * 2);
  _Float16* MtL = (_Float16*)alloc(8ull * 512 * KP * 2);
  _Float16* Akr = (_Float16*)alloc(6ull * 1024 * KP * 2);
  _Float16* Bt0 = (_Float16*)alloc(384ull * KP * 2);
  _Float16* Btl = (_Float16*)alloc(128ull * KP * 2);
  float* stA    = (float*)alloc(512ull * 2560 * 4);
  float* GN     = (float*)alloc(4096ull * 32 * 4);
  (void)ws_size; (void)in_sizes; (void)n_in; (void)out_size;

  prep_xh <<<25088, 256, 0, stream>>>(x, xh);
  prep_ckt<<<  128, 256, 0, stream>>>(cf, cm, cl, Ckt);
  prep_akr<<< 5376, 256, 0, stream>>>(tm, Akr);
  prep_bt0<<<  336, 256, 0, stream>>>(tf, Bt0);
  prep_btl<<<  112, 256, 0, stream>>>(tl, Btl);
  zero_pads<<<  768, 256, 0, stream>>>(Mt2, MtF, MtL);

  gemm_mfma<QP, 0><<<dim3(784, 4), 256, 0, stream>>>(Ckt, xh, Mt2, MtF, MtL);
  gemm_mfma<KP, 2><<<dim3(3, 32), 256, 0, stream>>>(MtF, Bt0, stA, nullptr, nullptr);
  gemm_mfma<KP, 3><<<dim3(1, 32), 256, 0, stream>>>(MtL, Btl, GN, nullptr, nullptr);

  chain_kernel<<<512, 256, 0, stream>>>(Mt2, Akr, stA, GN, out);
}

// Round 9
// 265.943 us; speedup vs baseline: 1.1507x; 1.0194x over previous
//
#include <hip/hip_runtime.h>

// TensorConvolutionTrainLayer: S=512,P=196,Q=48,CB=8,R=32,C=10,N=8
// R12: attack the NON-chain 151 us (chain is 120 us and two ILP attacks were
// neutral). Big GEMM (Ckt x xh -> Mt2/MtF/MtL) had a 64-scalar-2B-store
// epilogue (51M store instrs). Transpose it: compute xh x Ckt^T (swap A/B);
// M-side = sp = s*196+p, N-side = ab row. MFMA C-layout then gives each
// thread 4 CONSECUTIVE p at fixed ab row; sp tile bases are mult-of-4 and
// 196%4==0 -> p%4==0, p<=192: every store is one aligned half4 (b64), 16
// stores/thread, never crosses a row. prep_xh vectorized to half8/thread
// (grid 25088->3136); zero_pads vectorized to half4s. Chain = R11 verbatim.

typedef _Float16 half8 __attribute__((ext_vector_type(8)));
typedef _Float16 half4 __attribute__((ext_vector_type(4)));
typedef __fp16   fp16x2 __attribute__((ext_vector_type(2)));
typedef float floatx4 __attribute__((ext_vector_type(4)));

#define KP 224    // P padded to 7*32
#define QP 64     // Q padded to 2*32
#define LDA2 232  // Mt2/Ash row stride (halfs) = 29 x 16B chunks
#define GSTR 40   // Gsh row stride (halfs): 80B rows -> b128-aligned
#define SSTR 264  // St3 row stride (halfs): 528B, 16B-aligned

__device__ __forceinline__ void gld_lds16(const void* g, void* l) {
  __builtin_amdgcn_global_load_lds((const __attribute__((address_space(1))) void*)g,
                                   (__attribute__((address_space(3))) void*)l, 16, 0, 0);
}

// ---------------- generic MFMA GEMM ----------------
// MODE 4: transposed big GEMM. A = xh [100352 x 64], Bt = Ckt [512 x 64].
//   C'[sp][ab]: thread holds 4 consecutive sp-rows?? no: 4 consecutive p at
//   fixed ab (r=0..3 along M-side = sp). Vector half4 stores into
//   Mt2 [s][ab-8][p] / MtF [ab][s][p] / MtL [ab-392][s][p].
template<int K, int MODE>
__global__ __launch_bounds__(256)
void gemm_mfma(const _Float16* __restrict__ A, const _Float16* __restrict__ Bt,
               void* __restrict__ out0, void* __restrict__ out1, void* __restrict__ out2)
{
  __shared__ __align__(16) _Float16 Ash[128 * 32];
  __shared__ __align__(16) _Float16 Bsh[128 * 32];
  const int tid  = threadIdx.x;
  const int wave = tid >> 6;
  const int lane = tid & 63;
  const int m0 = blockIdx.y * 128;
  const int n0 = blockIdx.x * 128;
  const int wm = (wave >> 1) * 64;
  const int wn = (wave & 1) * 64;
  const int fr = lane & 15;
  const int fq = lane >> 4;

  floatx4 acc[4][4] = {};

  for (int kt = 0; kt < K; kt += 32) {
    __syncthreads();
#pragma unroll
    for (int j = 0; j < 2; j++) {
      const int c   = j * 256 + tid;
      const int row = c >> 2;
      const int ko  = (c & 3) * 8;
      gld_lds16(A  + (size_t)(m0 + row) * K + kt + ko,
                (char*)Ash + (size_t)(j * 256 + wave * 64) * 16);
      gld_lds16(Bt + (size_t)(n0 + row) * K + kt + ko,
                (char*)Bsh + (size_t)(j * 256 + wave * 64) * 16);
    }
    __syncthreads();
    half8 af[4], bf[4];
#pragma unroll
    for (int i = 0; i < 4; i++)
      af[i] = *(const half8*)&Ash[(wm + i * 16 + fr) * 32 + fq * 8];
#pragma unroll
    for (int i = 0; i < 4; i++)
      bf[i] = *(const half8*)&Bsh[(wn + i * 16 + fr) * 32 + fq * 8];
#pragma unroll
    for (int i = 0; i < 4; i++)
#pragma unroll
      for (int j = 0; j < 4; j++)
        acc[i][j] = __builtin_amdgcn_mfma_f32_16x16x32_f16(af[i], bf[j], acc[i][j], 0, 0, 0);
  }

  if constexpr (MODE == 4) {
#pragma unroll
    for (int i = 0; i < 4; i++) {
      const int m = m0 + wm + i * 16 + fq * 4;        // sp base: multiple of 4
      const unsigned s = (unsigned)m / 196u;
      const unsigned p = (unsigned)m - s * 196u;      // %4==0 -> p<=192, no row cross
#pragma unroll
      for (int j = 0; j < 4; j++) {
        const int n = n0 + wn + j * 16 + fr;          // ab row
        half4 h;
#pragma unroll
        for (int r = 0; r < 4; r++) h[r] = (_Float16)acc[i][j][r];
        if (n < 8)
          *(half4*)&((_Float16*)out1)[((size_t)n * 512 + s) * KP + p] = h;
        else if (n < 392)
          *(half4*)&((_Float16*)out0)[((size_t)s * 384 + (n - 8)) * LDA2 + p] = h;
        else if (n < 400)
          *(half4*)&((_Float16*)out2)[((size_t)(n - 392) * 512 + s) * KP + p] = h;
      }
    }
    return;
  }

#pragma unroll
  for (int i = 0; i < 4; i++) {
#pragma unroll
    for (int j = 0; j < 4; j++) {
#pragma unroll
      for (int r = 0; r < 4; r++) {
        const int m = m0 + wm + i * 16 + fq * 4 + r;
        const int n = n0 + wn + j * 16 + fr;
        const float v = acc[i][j][r];
        if constexpr (MODE == 2) {
          if (n < 320)
            ((float*)out0)[(size_t)(m & 511) * 2560 + (m >> 9) * 320 + n] = v;
        } else {
          if (n < 32)
            ((float*)out0)[(size_t)m * 32 + n] = v;
        }
      }
    }
  }
}

// ---------------- fused chain kernel (R11 verbatim) ----------------
__device__ __forceinline__ void stageA(const _Float16* __restrict__ base,
                                       _Float16* __restrict__ ash, int tid) {
  const int wave = tid >> 6;
#pragma unroll
  for (int it = 0; it < 7; it++) {
    const int c = it * 256 + tid;
    gld_lds16(base + (size_t)c * 8, (char*)ash + (size_t)(it * 256 + wave * 64) * 16);
  }
  if (tid < 64)
    gld_lds16(base + (size_t)(1792 + tid) * 8, (char*)ash + (size_t)1792 * 16);
}

__global__ __launch_bounds__(256, 2)
void chain_kernel(const _Float16* __restrict__ Mt2, const _Float16* __restrict__ Akr,
                  const float* __restrict__ St0, const float* __restrict__ GN,
                  float* __restrict__ out)
{
  __shared__ __align__(16) _Float16 Ash[64 * LDA2];        // 29696 B
  __shared__ __align__(16) _Float16 Gsh[4][64 * GSTR];     // 20480 B (per-wave private)
  __shared__ __align__(16) _Float16 St3[16 * SSTR];        // 8448 B
  __shared__ float oc[10];

  const int tid  = threadIdx.x;
  const int wave = tid >> 6;
  const int lane = tid & 63;
  const int s    = blockIdx.x;
  const int fr   = lane & 15;
  const int fq   = lane >> 4;
  const int fre  = fr & 7;
  const int frh  = fr >> 3;
  const int fqh  = fq >> 1;
  const int fql  = fq & 1;

  // init: St3[c][r*8+sigma(b)] from St0[s][b*320+r*10+c]; tid=(b,r)
  {
    const int b = tid >> 5, r = tid & 31;
    const int kcol = r * 8 + ((b & 1) * 4 + (b >> 1));
    const float* src = St0 + (size_t)s * 2560 + (size_t)tid * 10;
#pragma unroll
    for (int c = 0; c < 10; c++) St3[c * SSTR + kcol] = (_Float16)src[c];
    if (tid < 10) oc[tid] = 0.f;
  }
  stageA(Mt2 + (size_t)s * 384 * LDA2, Ash, tid);

  // B lane offsets: G B-cols n = ni*16+fr -> l = ni*2+frh, rr = fre (wave's r-slice)
  const size_t lb0 = (size_t)((0 * 2 + frh) * 32 + wave * 8 + fre) * KP + fq * 8;
  const size_t lb1 = (size_t)((1 * 2 + frh) * 32 + wave * 8 + fre) * KP + fq * 8;

  // rolling B prefetch (2-deep): bq[kt&1][ni], preload (k=0, cc=0, kt=0,1)
  half8 bq[2][2];
#pragma unroll
  for (int t2 = 0; t2 < 2; t2++) {
    bq[t2][0] = *(const half8*)(Akr + lb0 + t2 * 32);
    bq[t2][1] = *(const half8*)(Akr + lb1 + t2 * 32);
  }
  __syncthreads();   // Ash + St3 ready (compiler drains vmcnt before barrier)

  _Float16* gw = &Gsh[wave][0];

  for (int k = 0; k < 6; k++) {
    // af hoist: whole 64x224 A-tile -> regs/AGPRs once per k (R5/R9-proven)
    half8 af[7][4];
#pragma unroll
    for (int kt = 0; kt < 7; kt++)
#pragma unroll
      for (int mi = 0; mi < 4; mi++)
        af[kt][mi] = *(const half8*)&Ash[(mi * 16 + fr) * LDA2 + kt * 32 + fq * 8];
    __syncthreads();   // bar1: af reads done -> Ash free; St3(k) visible
    if (k < 5) stageA(Mt2 + ((size_t)s * 384 + 64 * (k + 1)) * LDA2, Ash, tid);

    floatx4 ns[4] = {};

#pragma unroll 1
    for (int cc = 0; cc <= 8; cc++) {
      // ---- early reads for NS(cc-1): old Gsh data; program order places them
      // before this iteration's pack-writes, so a single buffer is safe ----
      half8 aaP[4], bsP;
      if (cc > 0) {
        bsP = *(const half8*)&St3[fr * SSTR + (cc - 1) * 32 + fq * 8];
#pragma unroll
        for (int t = 0; t < 4; t++)
          aaP[t] = *(const half8*)&gw[(t * 16 + fr) * GSTR + fq * 8];
        __builtin_amdgcn_sched_barrier(0);   // pin reads above the G train
      }

      floatx4 acc[4][2] = {};
      if (cc < 8) {
        const _Float16* Bc = Akr + ((size_t)k * 1024 + cc * 128) * KP;
        // ---- G-phase: wave's 64 ab x 32 (4l x own 8r) slice, K=224 ----
#pragma unroll
        for (int kt = 0; kt < 7; kt++) {
#pragma unroll
          for (int mi = 0; mi < 4; mi++) {
            acc[mi][0] = __builtin_amdgcn_mfma_f32_16x16x32_f16(af[kt][mi], bq[kt & 1][0], acc[mi][0], 0, 0, 0);
            acc[mi][1] = __builtin_amdgcn_mfma_f32_16x16x32_f16(af[kt][mi], bq[kt & 1][1], acc[mi][1], 0, 0, 0);
          }
          if (kt < 5) {   // rolling prefetch, distance 2 kt within the chunk
            bq[kt & 1][0] = *(const half8*)(Bc + lb0 + (kt + 2) * 32);
            bq[kt & 1][1] = *(const half8*)(Bc + lb1 + (kt + 2) * 32);
          }
        }
        // refill kt=0,1 of the NEXT chunk; NS+pack below cover the latency
        {
          int ncc = cc + 1, nk = k;
          if (ncc == 8) { ncc = 0; nk = k + 1; }
          if (nk < 6) {
            const _Float16* Bn = Akr + ((size_t)nk * 1024 + ncc * 128) * KP;
#pragma unroll
            for (int t2 = 0; t2 < 2; t2++) {
              bq[t2][0] = *(const half8*)(Bn + lb0 + t2 * 32);
              bq[t2][1] = *(const half8*)(Bn + lb1 + t2 * 32);
            }
          }
        }
      }

      // ---- NS(cc-1): registers ready (read latency covered by G train) ----
      if (cc > 0) {
#pragma unroll
        for (int t = 0; t < 4; t++)
          ns[t] = __builtin_amdgcn_mfma_f32_16x16x32_f16(aaP[t], bsP, ns[t], 0, 0, 0);
      }

      // ---- pack + write cc to PRIVATE Gsh (cvt_pkrtz: 2 f32 -> f16x2) ----
      if (cc < 8) {
#pragma unroll
        for (int ni = 0; ni < 2; ni++)
#pragma unroll
          for (int rg = 0; rg < 4; rg++) {
            union { half4 h4; fp16x2 p[2]; } u;
            u.p[0] = __builtin_amdgcn_cvt_pkrtz(acc[0][ni][rg], acc[1][ni][rg]);
            u.p[1] = __builtin_amdgcn_cvt_pkrtz(acc[2][ni][rg], acc[3][ni][rg]);
            *(half4*)&gw[((fql * 4 + rg) * 8 + fre) * GSTR + (ni * 2 + frh) * 8 + fqh * 4] = u.h4;
          }
      }
    }

    __syncthreads();   // bar2: all NS reads of St3 done; stage(k+1) drained
    // epilogue: ns -> St3 (wave-disjoint columns). m=t*16+fq*4+rg -> b=m>>3, rr=m&7
    if (fr < 10) {
#pragma unroll
      for (int t = 0; t < 4; t++) {
#pragma unroll
        for (int rg = 0; rg < 4; rg++) {
          const int m = t * 16 + fq * 4 + rg;
          const int b = m >> 3, rr = m & 7;
          St3[fr * SSTR + (wave * 8 + rr) * 8 + (b & 1) * 4 + (b >> 1)] = (_Float16)ns[t][rg];
        }
      }
    }
    // next k's bar1 orders these writes before any NS read of k+1
  }
  __syncthreads();

  // final: out[s,c] = sum_{a,l} St3[c][l*8+sigma(a)] * GN[a][s][l]
  {
    const int a = tid >> 5, l = tid & 31;
    const float gn = GN[((size_t)a * 512 + s) * 32 + l];
    const int kcol = l * 8 + ((a & 1) * 4 + (a >> 1));
#pragma unroll
    for (int c = 0; c < 10; c++) {
      float v = gn * (float)St3[c * SSTR + kcol];
#pragma unroll
      for (int o2 = 1; o2 < 64; o2 <<= 1) v += __shfl_xor(v, o2, 64);
      if (lane == 0) atomicAdd(&oc[c], v);
    }
    __syncthreads();
    if (tid < 10) out[(size_t)s * 10 + tid] = oc[tid];
  }
}

// ---------------- prep kernels ----------------
// vectorized: one half8 (16B) per thread; q-chunks of 8 never straddle q=48
__global__ void prep_xh(const float* __restrict__ x, _Float16* __restrict__ xh) {
  const int i8 = blockIdx.x * 256 + threadIdx.x;   // 802816 threads
  const int q8 = (i8 & 7) * 8, sp = i8 >> 3;
  half8 h = {};
  if (q8 < 48) {
    const float* src = x + (size_t)sp * 48 + q8;
#pragma unroll
    for (int j = 0; j < 8; j++) h[j] = (_Float16)src[j];
  }
  *(half8*)&xh[(size_t)sp * 64 + q8] = h;
}

__global__ void prep_ckt(const float* __restrict__ cf, const float* __restrict__ cm,
                         const float* __restrict__ cl, _Float16* __restrict__ Ckt) {
  const int idx = blockIdx.x * 256 + threadIdx.x;
  const int q = idx & 63;
  const int row = idx >> 6;
  float v = 0.f;
  if (q < 48) {
    if (row < 8) v = cf[q * 8 + row];
    else if (row < 392) {
      const int rr = row - 8;
      const int k = rr >> 6, ab = rr & 63, a = ab >> 3, b = ab & 7;
      v = cm[((k * 8 + a) * 48 + q) * 8 + b];
    } else if (row < 400) v = cl[(row - 392) * 48 + q];
  }
  Ckt[idx] = (_Float16)v;
}

__global__ void prep_akr(const float* __restrict__ tm, _Float16* __restrict__ Akr) {
  const int idx = blockIdx.x * 256 + threadIdx.x;
  const int p = idx % 224;
  const int lr = (idx / 224) & 1023;
  const int k = idx / (224 * 1024);
  const int l = lr >> 5, r = lr & 31;
  float v = 0.f;
  if (p < 196) v = tm[(((k * 32 + l) * 196) + p) * 32 + r];
  Akr[idx] = (_Float16)v;
}

__global__ void prep_bt0(const float* __restrict__ tf, _Float16* __restrict__ Bt0) {
  const int idx = blockIdx.x * 256 + threadIdx.x;
  const int p = idx % 224;
  const int n = idx / 224;
  float v = 0.f;
  if (n < 320 && p < 196) {
    const int r = n / 10, c = n % 10;
    v = tf[(c * 196 + p) * 32 + r];
  }
  Bt0[idx] = (_Float16)v;
}

__global__ void prep_btl(const float* __restrict__ tl, _Float16* __restrict__ Btl) {
  const int idx = blockIdx.x * 256 + threadIdx.x;
  const int p = idx % 224;
  const int n = idx / 224;
  float v = 0.f;
  if (n < 32 && p < 196) v = tl[n * 196 + p];
  Btl[idx] = (_Float16)v;
}

__global__ void zero_pads(_Float16* __restrict__ Mt2, _Float16* __restrict__ MtF,
                          _Float16* __restrict__ MtL) {
  const int idx = blockIdx.x * 256 + threadIdx.x;
  if (idx < 196608) {
    _Float16* p = Mt2 + (size_t)idx * LDA2 + 196;   // byte 392: 8B-aligned
#pragma unroll
    for (int j = 0; j < 9; j++) *(half4*)(p + j * 4) = half4{};
  }
  if (idx < 4096) {
    _Float16* pf = MtF + (size_t)idx * KP + 196;
    _Float16* ql = MtL + (size_t)idx * KP + 196;
#pragma unroll
    for (int j = 0; j < 7; j++) { *(half4*)(pf + j * 4) = half4{}; *(half4*)(ql + j * 4) = half4{}; }
  }
}

extern "C" void kernel_launch(void* const* d_in, const int* in_sizes, int n_in,
                              void* d_out, int out_size, void* d_ws, size_t ws_size,
                              hipStream_t stream)
{
  const float* x  = (const float*)d_in[0];
  const float* cf = (const float*)d_in[1];
  const float* cm = (const float*)d_in[2];
  const float* cl = (const float*)d_in[3];
  const float* tf = (const float*)d_in[4];
  const float* tm = (const float*)d_in[5];
  const float* tl = (const float*)d_in[6];
  float* out = (float*)d_out;

  char* w = (char*)d_ws;
  auto alloc = [&](size_t bytes) { char* p = w; w += (bytes + 255) & ~(size_t)255; return p; };
  _Float16* xh  = (_Float16*)alloc(100352ull * 64 * 2);
  _Float16* Ckt = (_Float16*)alloc(512ull * 64 * 2);
  _Float16* Mt2 = (_Float16*)alloc(512ull * 384 * LDA2 * 2);
  _Float16* MtF = (_Float16*)alloc(8ull * 512 * KP * 2);
  _Float16* MtL = (_Float16*)alloc(8ull * 512 * KP * 2);
  _Float16* Akr = (_Float16*)alloc(6ull * 1024 * KP * 2);
  _Float16* Bt0 = (_Float16*)alloc(384ull * KP * 2);
  _Float16* Btl = (_Float16*)alloc(128ull * KP * 2);
  float* stA    = (float*)alloc(512ull * 2560 * 4);
  float* GN     = (float*)alloc(4096ull * 32 * 4);
  (void)ws_size; (void)in_sizes; (void)n_in; (void)out_size;

  prep_xh <<< 3136, 256, 0, stream>>>(x, xh);
  prep_ckt<<<  128, 256, 0, stream>>>(cf, cm, cl, Ckt);
  prep_akr<<< 5376, 256, 0, stream>>>(tm, Akr);
  prep_bt0<<<  336, 256, 0, stream>>>(tf, Bt0);
  prep_btl<<<  112, 256, 0, stream>>>(tl, Btl);
  zero_pads<<<  768, 256, 0, stream>>>(Mt2, MtF, MtL);

  // transposed big GEMM: A = xh (M side = 100352), Bt = Ckt (N side = 512)
  gemm_mfma<QP, 4><<<dim3(4, 784), 256, 0, stream>>>(xh, Ckt, Mt2, MtF, MtL);
  gemm_mfma<KP, 2><<<dim3(3, 32), 256, 0, stream>>>(MtF, Bt0, stA, nullptr, nullptr);
  gemm_mfma<KP, 3><<<dim3(1, 32), 256, 0, stream>>>(MtL, Btl, GN, nullptr, nullptr);

  chain_kernel<<<512, 256, 0, stream>>>(Mt2, Akr, stA, GN, out);
}